// Round 3
// baseline (1760.407 us; speedup 1.0000x reference)
//
#include <hip/hip_runtime.h>
#include <hip/hip_cooperative_groups.h>
#include <math.h>

namespace cg = cooperative_groups;

// Boltzmann machine sequential Gibbs sweep, N=8192, single cooperative kernel.
// Per block b of 512 scan positions:
//   Phase A: WG0 runs the serial scan of block b (Sraw_b already corrected);
//            WGs 1..255 compute panel b+1 matvec vs state_pre_b (fp64 accum)
//            and gather tiles (b+1,b+1) [diag, for next scan] and (b+1,b)
//            [off-diag, for the correction].
//   Phase B: grid-wide rank-512 correction Sraw_{b+1} += tile(b+1,b)*del_b,
//            and state update for block b's units.
// Decision: u <= sigmoid(s/T) <=> s >= T*log(u/(1-u)), thr fp64,
// rand_u is SCAN-POSITION indexed; clamping/state are UNIT indexed.

#define NN 8192
#define BB 512
#define NBLK 16
#define SUB 64
#define NSUB 8
#define NWG 256
#define TPB 256

__device__ __forceinline__ void matvec_panel(
    const float* __restrict__ w, const float* __restrict__ state,
    const int* __restrict__ perm, int b, double* __restrict__ S,
    float* __restrict__ tD, float* __restrict__ tO,
    int wgi, int nwg, int tid, double* redL)
{
    for (int r = wgi; r < BB; r += nwg) {
        int row = perm[b * BB + r];
        const float4* wr = (const float4*)(w + (size_t)row * NN);
        const float4* st = (const float4*)state;
        double acc = 0.0;
#pragma unroll
        for (int k = 0; k < NN / (4 * TPB); ++k) {   // 8 iters
            float4 wv = wr[tid + k * TPB];
            float4 sv = st[tid + k * TPB];
            acc += (double)(wv.x * sv.x) + (double)(wv.y * sv.y) +
                   (double)(wv.z * sv.z) + (double)(wv.w * sv.w);
        }
        redL[tid] = acc;
        __syncthreads();
        for (int off = TPB / 2; off > 0; off >>= 1) {
            if (tid < off) redL[tid] += redL[tid + off];
            __syncthreads();
        }
        if (tid == 0) S[r] = redL[0];
        __syncthreads();   // protect redL before next row reuses it
        // gather tiles; row is L1/L2-hot from the stream above
        const float* wrow = w + (size_t)row * NN;
        for (int s = tid; s < BB; s += TPB) {
            tD[(size_t)r * BB + s] = wrow[perm[b * BB + s]];
            if (tO) tO[(size_t)r * BB + s] = wrow[perm[(b - 1) * BB + s]];
        }
    }
}

__device__ __forceinline__ void scan_block(
    int b, const double* __restrict__ S, const float* __restrict__ tD,
    const double* __restrict__ thr, const float* __restrict__ state,
    const float* __restrict__ clampv, const int* __restrict__ perm,
    float* __restrict__ del, double* sumsL, double* thrL,
    float* d1L, float* d0L, float* delL, int tid)
{
    for (int t = tid; t < BB; t += TPB) {
        int unit = perm[b * BB + t];
        sumsL[t] = S[t];
        thrL[t] = thr[b * BB + t];          // position-indexed
        float old = state[unit];
        bool cl = (clampv[unit] != 0.0f);
        d1L[t] = cl ? 0.0f : (1.0f - old);  // delta if decision==1
        d0L[t] = cl ? 0.0f : (0.0f - old);  // delta if decision==0
    }
    __syncthreads();

    for (int t8 = 0; t8 < NSUB; ++t8) {
        if (tid < 64) {   // wave 0: 64-step lockstep sub-scan
            int idx = t8 * SUB + tid;
            const float4* mrow = (const float4*)(tD + (size_t)idx * BB + t8 * SUB);
            float m[SUB];
#pragma unroll
            for (int j = 0; j < SUB / 4; ++j) {
                float4 mv = mrow[j];
                m[4 * j] = mv.x; m[4 * j + 1] = mv.y;
                m[4 * j + 2] = mv.z; m[4 * j + 3] = mv.w;
            }
            double sum = sumsL[idx];
            double th = thrL[idx];
            float d1 = d1L[idx], d0 = d0L[idx];
            float mydelta = 0.0f;
#pragma unroll
            for (int s = 0; s < SUB; ++s) {
                float down = (sum >= th) ? d1 : d0;
                float sd = __shfl(down, s, 64);
                if (s == tid) mydelta = down;
                sum += (double)(m[s] * sd);   // exact fp32 product
            }
            delL[idx] = mydelta;
        }
        __syncthreads();
        // rank-64 fp64 update of remaining positions
        for (int r = t8 * SUB + SUB + tid; r < BB; r += TPB) {
            const float4* mr = (const float4*)(tD + (size_t)r * BB + t8 * SUB);
            double acc = sumsL[r];
#pragma unroll
            for (int j = 0; j < SUB / 4; ++j) {
                float4 mv = mr[j];
                acc += (double)(mv.x * delL[t8 * SUB + 4 * j]) +
                       (double)(mv.y * delL[t8 * SUB + 4 * j + 1]) +
                       (double)(mv.z * delL[t8 * SUB + 4 * j + 2]) +
                       (double)(mv.w * delL[t8 * SUB + 4 * j + 3]);
            }
            sumsL[r] = acc;
        }
        __syncthreads();
    }
    for (int t = tid; t < BB; t += TPB) del[t] = delL[t];
}

__global__ __launch_bounds__(TPB) void k_gibbs(
    const float* __restrict__ w, const float* __restrict__ init,
    const float* __restrict__ clampv, const float* __restrict__ Tp,
    const int* __restrict__ perm, const float* __restrict__ urand,
    float* __restrict__ state, double* __restrict__ thr,
    double* __restrict__ Sbuf0, double* __restrict__ Sbuf1,
    float* __restrict__ del, float* __restrict__ tD0,
    float* __restrict__ tD1, float* __restrict__ tO)
{
    cg::grid_group grid = cg::this_grid();
    const int wg = blockIdx.x, tid = threadIdx.x;
    const int gtid = wg * TPB + tid;

    __shared__ double redL[TPB];
    __shared__ double sumsL[BB], thrL[BB];
    __shared__ float d1L[BB], d0L[BB], delL[BB];

    // ---- prep: state copy + thresholds ----
    for (int i = gtid; i < NN; i += NWG * TPB) {
        state[i] = init[i];
        double u = (double)urand[i];
        thr[i] = (double)Tp[0] * log(u / (1.0 - u));  // u==0 -> -inf -> always 1
    }
    grid.sync();

    // ---- initial panel 0 (all WGs) ----
    matvec_panel(w, state, perm, 0, Sbuf0, tD0, nullptr, wg, NWG, tid, redL);
    grid.sync();

    double* Scur = Sbuf0; double* Snxt = Sbuf1;
    float* tDcur = tD0;   float* tDnxt = tD1;

    for (int b = 0; b < NBLK; ++b) {
        // ---- Phase A: scan(b) on WG0  ||  matvec panel b+1 on WGs 1..255 ----
        if (wg == 0) {
            scan_block(b, Scur, tDcur, thr, state, clampv, perm, del,
                       sumsL, thrL, d1L, d0L, delL, tid);
        } else if (b + 1 < NBLK) {
            matvec_panel(w, state, perm, b + 1, Snxt, tDnxt, tO,
                         wg - 1, NWG - 1, tid, redL);
        }
        grid.sync();

        // ---- Phase B: rank-512 correction + state update ----
        if (b + 1 < NBLK) {
            int grp = gtid >> 4;        // 16 threads per row
            int l16 = gtid & 15;
            if (grp < BB) {
                const float4* tr = (const float4*)(tO + (size_t)grp * BB + l16 * 32);
                double acc = 0.0;
#pragma unroll
                for (int j = 0; j < 8; ++j) {
                    float4 tv = tr[j];
                    acc += (double)(tv.x * del[l16 * 32 + 4 * j]) +
                           (double)(tv.y * del[l16 * 32 + 4 * j + 1]) +
                           (double)(tv.z * del[l16 * 32 + 4 * j + 2]) +
                           (double)(tv.w * del[l16 * 32 + 4 * j + 3]);
                }
                for (int off = 8; off > 0; off >>= 1)
                    acc += __shfl_down(acc, off, 16);
                if (l16 == 0) Snxt[grp] += acc;
            }
        }
        if (gtid < BB) {
            int u_ = perm[b * BB + gtid];
            state[u_] += del[gtid];     // exact: values in {0,1}
        }
        grid.sync();

        double* ts = Scur; Scur = Snxt; Snxt = ts;
        float* tf = tDcur; tDcur = tDnxt; tDnxt = tf;
    }
}

extern "C" void kernel_launch(void* const* d_in, const int* in_sizes, int n_in,
                              void* d_out, int out_size, void* d_ws, size_t ws_size,
                              hipStream_t stream) {
    const float* w      = (const float*)d_in[0];
    const float* init   = (const float*)d_in[1];
    const float* clampv = (const float*)d_in[2];
    const float* Tp     = (const float*)d_in[3];
    const int*   perm   = (const int*)d_in[4];
    const float* urand  = (const float*)d_in[5];

    float* state = (float*)d_out;                 // live state == output
    double* thr   = (double*)d_ws;                // NN
    double* Sbuf0 = thr + NN;                     // BB
    double* Sbuf1 = Sbuf0 + BB;                   // BB
    float*  del   = (float*)(Sbuf1 + BB);         // BB
    float*  tD0   = del + BB;                     // BB*BB
    float*  tD1   = tD0 + (size_t)BB * BB;        // BB*BB
    float*  tO    = tD1 + (size_t)BB * BB;        // BB*BB

    void* args[] = {(void*)&w, (void*)&init, (void*)&clampv, (void*)&Tp,
                    (void*)&perm, (void*)&urand, (void*)&state, (void*)&thr,
                    (void*)&Sbuf0, (void*)&Sbuf1, (void*)&del,
                    (void*)&tD0, (void*)&tD1, (void*)&tO};
    hipLaunchCooperativeKernel((const void*)k_gibbs, dim3(NWG), dim3(TPB),
                               args, 0, stream);
}

// Round 4
// 977.634 us; speedup vs baseline: 1.8007x; 1.8007x over previous
//
#include <hip/hip_runtime.h>
#include <math.h>

// Boltzmann Gibbs sweep N=8192, single cooperative kernel, flag-based pipeline.
// WG0 = producer: serial scans (block b). Workers (255 WGs) = panels/tiles/corrections.
//   worker iter b: panel(b+1) vs state_{<=b-1}  ||  WG0 scans block b
//                  then correct S[b+1] += tile(b+1,b)*del_b once del_b published.
// Sync: per-WG release-store slots + WG0 parallel poll; __threadfence (wbl2+inv)
// instead of cg::grid.sync (~40us each on 8-XCD MI355X -> round-3 regression).
// Decision: u <= sigmoid(s/T) <=> s >= T*log(u/(1-u)); thr fp64, position-indexed
// (lax.scan zips (perm, rand_u)); clamping/state unit-indexed; each unit visited
// exactly once (perm is a permutation) so d1/d0 precomputable from init.

#define NN 8192
#define BB 512
#define NBLK 16
#define SUB 64
#define NSUB 8
#define NWG 256
#define NWORK (NWG - 1)
#define TPB 512

typedef unsigned int u32;

__global__ void k_init(u32* flags, int n) {
  int i = blockIdx.x * blockDim.x + threadIdx.x;
  for (; i < n; i += gridDim.x * blockDim.x) flags[i] = 0;
}

__device__ __forceinline__ void wait_flag(const u32* p) {
  if (threadIdx.x == 0) {
    while (__hip_atomic_load(p, __ATOMIC_RELAXED, __HIP_MEMORY_SCOPE_AGENT) == 0u)
      __builtin_amdgcn_s_sleep(2);
    __threadfence();   // inv: make producer's flushed data visible
  }
  __syncthreads();
}

__device__ __forceinline__ void publish_flag(u32* p) {
  __syncthreads();     // all WG stores retired (vmcnt drain at barrier)
  if (threadIdx.x == 0) {
    __threadfence();   // wbl2: flush our stores to L3
    __hip_atomic_store(p, 1u, __ATOMIC_RELAXED, __HIP_MEMORY_SCOPE_AGENT);
  }
}

__device__ __forceinline__ void wg0_wait_all(const u32* slots) {
  int t = threadIdx.x;
  for (;;) {
    int ok = 1;
    if (t < NWORK)
      ok = (__hip_atomic_load(&slots[t], __ATOMIC_RELAXED, __HIP_MEMORY_SCOPE_AGENT) != 0u);
    if (__syncthreads_and(ok)) break;
    __builtin_amdgcn_s_sleep(2);
  }
  if (threadIdx.x == 0) __threadfence();
  __syncthreads();
}

// ---- worker: panel matvec (fp64 accum) + tile gathers ----
__device__ void worker_panel(const float* __restrict__ w, const float* __restrict__ stvec,
                             const int* __restrict__ perm, int pb,
                             double* __restrict__ S, float* __restrict__ tD,
                             float* __restrict__ tO, int wg, int tid, double* redL) {
  const int* permP = perm + pb * BB;
  const int* permO = (pb > 0) ? (perm + (pb - 1) * BB) : nullptr;
  int wv = tid >> 6, lane = tid & 63;
  for (int r = wg - 1; r < BB; r += NWORK) {
    int row = permP[r];
    const float4* wr = (const float4*)(w + (size_t)row * NN);
    const float4* sv = (const float4*)stvec;
    double acc = 0.0;
#pragma unroll
    for (int k = 0; k < NN / (4 * TPB); ++k) {  // 4 iters
      float4 a = wr[tid + k * TPB];
      float4 s = sv[tid + k * TPB];
      acc += (double)(a.x * s.x) + (double)(a.y * s.y) +
             (double)(a.z * s.z) + (double)(a.w * s.w);
    }
    for (int o = 32; o > 0; o >>= 1) acc += __shfl_down(acc, o, 64);
    if (lane == 0) redL[wv] = acc;
    __syncthreads();
    if (tid == 0) {
      double t = 0.0;
      for (int i = 0; i < TPB / 64; ++i) t += redL[i];
      S[r] = t;
    }
    // tile gathers: row is hot in this WG's L1/L2
    const float* wrow = w + (size_t)row * NN;
    if (tid < BB) {
      tD[(size_t)r * BB + tid] = wrow[permP[tid]];
      if (permO) tO[(size_t)r * BB + tid] = wrow[permO[tid]];
    }
    __syncthreads();  // protect redL before reuse
  }
}

// ---- worker: rank-512 correction S[r] += tileO[r] . del  (one row per wave) ----
__device__ void worker_correct(const float* __restrict__ tO, const float* __restrict__ del,
                               double* __restrict__ S, int wg, int tid) {
  int wvg = (wg - 1) * (TPB / 64) + (tid >> 6);
  int lane = tid & 63;
  if (wvg < BB) {
    int r = wvg;
    const float4* trow = (const float4*)(tO + (size_t)r * BB + lane * 8);
    const float4* dv   = (const float4*)(del + lane * 8);
    float4 t0 = trow[0], t1 = trow[1];
    float4 e0 = dv[0],   e1 = dv[1];
    double acc = (double)(t0.x * e0.x) + (double)(t0.y * e0.y) +
                 (double)(t0.z * e0.z) + (double)(t0.w * e0.w) +
                 (double)(t1.x * e1.x) + (double)(t1.y * e1.y) +
                 (double)(t1.z * e1.z) + (double)(t1.w * e1.w);
    for (int o = 32; o > 0; o >>= 1) acc += __shfl_down(acc, o, 64);
    if (lane == 0) S[r] += acc;   // single writer per row
  }
}

// ---- WG0: scan one block; wave0 serial sub-scans, waves1-7 pipelined rank updates ----
__device__ void scan_block_wg0(int b, const double* __restrict__ Sb,
                               const float* __restrict__ tDb, const double* __restrict__ thr,
                               const float* __restrict__ d1a, const float* __restrict__ d0a,
                               float* __restrict__ delG,
                               double* sumsL, double* thrL, float* d1L, float* d0L, float* delL) {
  int tid = threadIdx.x;
  if (tid < BB) {
    sumsL[tid] = Sb[tid];
    thrL[tid]  = thr[b * BB + tid];
    d1L[tid]   = d1a[b * BB + tid];
    d0L[tid]   = d0a[b * BB + tid];
  }
  __syncthreads();
  for (int t8 = 0; t8 < NSUB; ++t8) {
    if (tid < SUB) {
      int lane = tid;
      int row = t8 * SUB + lane;
      // issue diagonal m-loads early (L3 latency hidden under self-update)
      const float4* mc4 = (const float4*)(tDb + (size_t)row * BB + t8 * SUB);
      float m[SUB];
#pragma unroll
      for (int j = 0; j < SUB / 4; ++j) {
        float4 v = mc4[j];
        m[4*j] = v.x; m[4*j+1] = v.y; m[4*j+2] = v.z; m[4*j+3] = v.w;
      }
      double sum = sumsL[row];
      if (t8 > 0) {  // self-update with previous sub-block's deltas
        const float* mp = tDb + (size_t)row * BB + (t8 - 1) * SUB;
#pragma unroll
        for (int s = 0; s < SUB; ++s)
          sum += (double)(mp[s] * delL[(t8 - 1) * SUB + s]);
      }
      double th = thrL[row];
      float dd1 = d1L[row], dd0 = d0L[row];
      float mydel = 0.0f;
#pragma unroll
      for (int s = 0; s < SUB; ++s) {
        float down = (sum >= th) ? dd1 : dd0;
        float sd = __uint_as_float(__builtin_amdgcn_readlane(__float_as_uint(down), s));
        if (s == lane) mydel = down;
        sum += (double)(m[s] * sd);   // exact fp32 product into fp64
      }
      delL[row] = mydel;
      delG[b * BB + row] = mydel;
    } else if (t8 > 0) {
      // waves 1..7: apply delta(t8-1) to rows beyond the current sub-block
      for (int r = (t8 + 1) * SUB + (tid - SUB); r < BB; r += (TPB - SUB)) {
        const float* mp = tDb + (size_t)r * BB + (t8 - 1) * SUB;
        double acc = sumsL[r];
#pragma unroll
        for (int s = 0; s < SUB; ++s)
          acc += (double)(mp[s] * delL[(t8 - 1) * SUB + s]);
        sumsL[r] = acc;
      }
    }
    __syncthreads();
  }
}

__global__ __launch_bounds__(TPB) void k_gibbs(
    const float* __restrict__ w, const float* __restrict__ init,
    const float* __restrict__ clampv, const float* __restrict__ Tp,
    const int* __restrict__ perm, const float* __restrict__ urand,
    float* __restrict__ state, double* __restrict__ thr, double* __restrict__ S,
    float* __restrict__ d1a, float* __restrict__ d0a, float* __restrict__ delG,
    float* __restrict__ tileD, float* __restrict__ tileO,
    u32* slotPanel, u32* slotCorr, u32* delReady) {
  __shared__ double sumsL[BB];
  __shared__ double thrL[BB];
  __shared__ float d1L[BB], d0L[BB], delL[BB];
  __shared__ double redL[TPB / 64];
  int wg = blockIdx.x, tid = threadIdx.x;

  if (wg == 0) {
    // prologue: thresholds + clamped/flip deltas, all 8192 positions
    double T = (double)Tp[0];
    for (int i = tid; i < NN; i += TPB) {
      int u = perm[i];
      double uu = (double)urand[i];
      thr[i] = T * log(uu / (1.0 - uu));   // u==0 -> -inf -> always set to 1
      float old = init[u];
      bool cl = (clampv[u] != 0.0f);
      d1a[i] = cl ? 0.0f : (1.0f - old);
      d0a[i] = cl ? 0.0f : (0.0f - old);
    }
    __syncthreads();
    if (tid == 0) __threadfence();   // flush thr/d1/d0 so later invs re-read from L3
    __syncthreads();

    for (int b = 0; b < NBLK; ++b) {
      if (b == 0) wg0_wait_all(slotPanel);                       // panel 0 ready
      else        wg0_wait_all(slotCorr + (size_t)b * NWORK);    // S[b] corrected
      scan_block_wg0(b, S + (size_t)b * BB, tileD + (size_t)b * BB * BB,
                     thr, d1a, d0a, delG, sumsL, thrL, d1L, d0L, delL);
      if (b + 1 < NBLK) wg0_wait_all(slotPanel + (size_t)(b + 1) * NWORK);
      if (tid < BB) state[perm[b * BB + tid]] += delL[tid];      // exact {0,1}
      if (b + 1 < NBLK) publish_flag(&delReady[b]);
      else __syncthreads();
    }
  } else {
    // worker prologue: state copy + panel 0 (vs init, race-free) + diag tile 0
    for (int i = (wg - 1) * TPB + tid; i < NN; i += NWORK * TPB) state[i] = init[i];
    worker_panel(w, init, perm, 0, S, tileD, nullptr, wg, tid, redL);
    publish_flag(&slotPanel[wg - 1]);

    for (int b = 0; b < NBLK - 1; ++b) {
      if (b > 0) wait_flag(&delReady[b - 1]);        // state updated through b-1
      const float* stv = (b == 0) ? init : state;
      worker_panel(w, stv, perm, b + 1, S + (size_t)(b + 1) * BB,
                   tileD + (size_t)(b + 1) * BB * BB,
                   tileO + (size_t)(b + 1) * BB * BB, wg, tid, redL);
      publish_flag(&slotPanel[(size_t)(b + 1) * NWORK + (wg - 1)]);
      wait_flag(&delReady[b]);                       // del_b available
      worker_correct(tileO + (size_t)(b + 1) * BB * BB, delG + b * BB,
                     S + (size_t)(b + 1) * BB, wg, tid);
      publish_flag(&slotCorr[(size_t)(b + 1) * NWORK + (wg - 1)]);
    }
  }
}

extern "C" void kernel_launch(void* const* d_in, const int* in_sizes, int n_in,
                              void* d_out, int out_size, void* d_ws, size_t ws_size,
                              hipStream_t stream) {
  const float* w      = (const float*)d_in[0];
  const float* init   = (const float*)d_in[1];
  const float* clampv = (const float*)d_in[2];
  const float* Tp     = (const float*)d_in[3];
  const int*   perm   = (const int*)d_in[4];
  const float* urand  = (const float*)d_in[5];

  float* state = (float*)d_out;
  double* thr  = (double*)d_ws;                          // NN
  double* S    = thr + NN;                               // NBLK*BB
  float* d1a   = (float*)(S + (size_t)NBLK * BB);        // NN
  float* d0a   = d1a + NN;                               // NN
  float* delG  = d0a + NN;                               // NN
  float* tileD = delG + NN;                              // NBLK*BB*BB
  float* tileO = tileD + (size_t)NBLK * BB * BB;         // NBLK*BB*BB
  u32* slotPanel = (u32*)(tileO + (size_t)NBLK * BB * BB);  // NBLK*NWORK
  u32* slotCorr  = slotPanel + NBLK * NWORK;                // NBLK*NWORK
  u32* delReady  = slotCorr + NBLK * NWORK;                 // NBLK

  int nflags = NBLK * NWORK * 2 + NBLK;
  k_init<<<8, 256, 0, stream>>>(slotPanel, nflags);

  void* args[] = {(void*)&w, (void*)&init, (void*)&clampv, (void*)&Tp,
                  (void*)&perm, (void*)&urand, (void*)&state, (void*)&thr,
                  (void*)&S, (void*)&d1a, (void*)&d0a, (void*)&delG,
                  (void*)&tileD, (void*)&tileO,
                  (void*)&slotPanel, (void*)&slotCorr, (void*)&delReady};
  hipLaunchCooperativeKernel((const void*)k_gibbs, dim3(NWG), dim3(TPB),
                             args, 0, stream);
}

// Round 5
// 777.616 us; speedup vs baseline: 2.2639x; 1.2572x over previous
//
#include <hip/hip_runtime.h>
#include <math.h>

// Boltzmann Gibbs sweep N=8192. Single cooperative kernel, flag pipeline.
// BB=1024 blocks (8): WG0 scans block b while 255 workers build panel b+1
// (dot vs their PRIVATE LDS state copy) + gather coupling tiles; workers
// correct S[b+1] with del_b. Cross-WG data (tiles/S/delG/thr) moves via
// agent-scope write-through atomic stores -> L2 stays clean -> fences cheap.
// Decision: u <= sigmoid(s/T) <=> s >= T*log(u/(1-u)); thr fp64,
// POSITION-indexed (lax.scan zips (perm, rand_u)); clamp/state UNIT-indexed.
// All sums fp64; every correction product w*delta is exact in fp32.

#define NN 8192
#define BB 1024
#define NBLK 8
#define SUB 64
#define NSUB 16
#define NWG 256
#define NWORK 255
#define TPB 512
#define MAXROWS 5

typedef unsigned int u32;

__global__ void k_init(u32* flags, int n) {
  int i = blockIdx.x * blockDim.x + threadIdx.x;
  for (; i < n; i += gridDim.x * blockDim.x) flags[i] = 0;
}

__device__ __forceinline__ void st_f32(float* p, float v) {
  __hip_atomic_store(p, v, __ATOMIC_RELAXED, __HIP_MEMORY_SCOPE_AGENT);
}
__device__ __forceinline__ void st_f64(double* p, double v) {
  __hip_atomic_store(p, v, __ATOMIC_RELAXED, __HIP_MEMORY_SCOPE_AGENT);
}

__device__ __forceinline__ void wait_flag(const u32* p) {
  if (threadIdx.x == 0) {
    while (__hip_atomic_load(p, __ATOMIC_RELAXED, __HIP_MEMORY_SCOPE_AGENT) == 0u)
      __builtin_amdgcn_s_sleep(2);
    __threadfence();
  }
  __syncthreads();
}

__device__ __forceinline__ void publish_flag(u32* p) {
  __syncthreads();
  if (threadIdx.x == 0) {
    __threadfence();
    __hip_atomic_store(p, 1u, __ATOMIC_RELAXED, __HIP_MEMORY_SCOPE_AGENT);
  }
  __syncthreads();
}

__device__ __forceinline__ void wg0_wait_all(const u32* slots) {
  int t = threadIdx.x;
  for (;;) {
    int ok = 1;
    if (t < NWORK)
      ok = (__hip_atomic_load(&slots[t], __ATOMIC_RELAXED, __HIP_MEMORY_SCOPE_AGENT) != 0u);
    if (__syncthreads_and(ok)) break;
    __builtin_amdgcn_s_sleep(2);
  }
  if (threadIdx.x == 0) __threadfence();
  __syncthreads();
}

__global__ __launch_bounds__(TPB) void k_gibbs(
    const float* __restrict__ w, const float* __restrict__ init,
    const float* __restrict__ clampv, const float* __restrict__ Tp,
    const int* __restrict__ perm, const float* __restrict__ urand,
    float* __restrict__ dout,
    double* __restrict__ thrG, double* __restrict__ S,
    float* __restrict__ d1G, float* __restrict__ d0G,
    float* __restrict__ delG, float* __restrict__ tileD,
    u32* slotCorr, u32* delReady) {
  __shared__ float stateL[NN];                       // workers: 32 KB
  __shared__ double sumsL[BB];                       // WG0: 8 KB
  __shared__ double thrL[BB];                        // 8 KB
  __shared__ float d1L[BB], d0L[BB], delL[BB];       // 12 KB
  __shared__ double redL[8][MAXROWS];                // 320 B
  const int wg = blockIdx.x, tid = threadIdx.x;
  const int wv = tid >> 6, lane = tid & 63;

  if (wg == 0) {
    // ---- prologue: thresholds + flip deltas (position-indexed) ----
    double T = (double)Tp[0];
    for (int i = tid; i < NN; i += TPB) {
      int unit = perm[i];
      double uu = (double)urand[i];
      st_f64(&thrG[i], T * log(uu / (1.0 - uu)));   // u==0 -> -inf -> always 1
      float old = init[unit];
      bool cl = (clampv[unit] != 0.0f);
      st_f32(&d1G[i], cl ? 0.0f : (1.0f - old));
      st_f32(&d0G[i], cl ? 0.0f : (0.0f - old));
    }
    __syncthreads();

    for (int b = 0; b < NBLK; ++b) {
      wg0_wait_all(slotCorr + (size_t)b * NWORK);    // S[b] fully corrected
      for (int i = tid; i < BB; i += TPB) {
        sumsL[i] = S[(size_t)b * BB + i];
        thrL[i]  = thrG[b * BB + i];
        d1L[i]   = d1G[b * BB + i];
        d0L[i]   = d0G[b * BB + i];
      }
      __syncthreads();
      const float* tb = tileD + (size_t)b * BB * BB;

      for (int t8 = 0; t8 < NSUB; ++t8) {
        float m[SUB];
        if (tid < SUB) {
          // issue diagonal m-loads (hidden under near-pass)
          const float4* mr = (const float4*)(tb + (size_t)(t8 * SUB + tid) * BB + t8 * SUB);
#pragma unroll
          for (int j = 0; j < SUB / 4; ++j) {
            float4 v = mr[j];
            m[4*j] = v.x; m[4*j+1] = v.y; m[4*j+2] = v.z; m[4*j+3] = v.w;
          }
        } else if (t8 > 0) {
          // near-pass: apply del(t8-1) to the 64 rows about to be scanned
          int t = tid - SUB, g = t >> 2, sub = t & 3;
          if (g < SUB) {
            int row = t8 * SUB + g;
            int c0 = (t8 - 1) * SUB + sub * 16;
            const float4* mr2 = (const float4*)(tb + (size_t)row * BB + c0);
            double p = 0.0;
#pragma unroll
            for (int j = 0; j < 4; ++j) {
              float4 v = mr2[j];
              p += (double)(v.x * delL[c0+4*j])   + (double)(v.y * delL[c0+4*j+1]) +
                   (double)(v.z * delL[c0+4*j+2]) + (double)(v.w * delL[c0+4*j+3]);
            }
            p += __shfl_down(p, 2, 4);
            p += __shfl_down(p, 1, 4);
            if (sub == 0) sumsL[row] += p;
          }
        }
        __syncthreads();
        if (tid < SUB) {
          // serial 64-step sub-scan (wave 0)
          int row = t8 * SUB + tid;
          double sum = sumsL[row], th = thrL[row];
          float dd1 = d1L[row], dd0 = d0L[row];
          float mydel = 0.0f;
          __builtin_amdgcn_s_setprio(3);
#pragma unroll
          for (int s = 0; s < SUB; ++s) {
            float down = (sum >= th) ? dd1 : dd0;
            float sd = __uint_as_float(__builtin_amdgcn_readlane(__float_as_uint(down), s));
            if (s == tid) mydel = down;
            sum += (double)(m[s] * sd);            // exact fp32 product
          }
          __builtin_amdgcn_s_setprio(0);
          delL[row] = mydel;
        } else if (t8 > 0) {
          // far-pass: apply del(t8-1) to rows beyond the current sub-block
          for (int r = (t8 + 1) * SUB + (tid - SUB); r < BB; r += (TPB - SUB)) {
            int c0 = (t8 - 1) * SUB;
            const float4* mr3 = (const float4*)(tb + (size_t)r * BB + c0);
            double acc = sumsL[r];
#pragma unroll
            for (int j = 0; j < SUB / 4; ++j) {
              float4 v = mr3[j];
              acc += (double)(v.x * delL[c0+4*j])   + (double)(v.y * delL[c0+4*j+1]) +
                     (double)(v.z * delL[c0+4*j+2]) + (double)(v.w * delL[c0+4*j+3]);
            }
            sumsL[r] = acc;
          }
        }
        __syncthreads();
      }
      // epilogue: publish deltas, then write output block
      for (int i = tid; i < BB; i += TPB) st_f32(&delG[b * BB + i], delL[i]);
      if (b + 1 < NBLK) publish_flag(&delReady[b]); else __syncthreads();
      for (int i = tid; i < BB; i += TPB) {
        int unit = perm[b * BB + i];
        st_f32(&dout[unit], init[unit] + delL[i]);   // exact {0,1} or clamped init
      }
    }
  } else {
    // ================= workers =================
    const int iw = wg - 1;
    const int start = (iw * BB) / NWORK, end = ((iw + 1) * BB) / NWORK;
    const int cnt = end - start;                     // 4..5
    for (int i = tid; i < NN; i += TPB) stateL[i] = init[i];
    __syncthreads();

    for (int pb = 0; pb < NBLK; ++pb) {
      const int b = pb - 1;                          // correction-del index
      int pcA = perm[pb * BB + tid];                 // tile cols (own block)
      int pcB = perm[pb * BB + tid + 512];
      int ppc[16];                                   // corr cols (prev block)
      if (pb > 0) {
#pragma unroll
        for (int j = 0; j < 16; ++j) ppc[j] = perm[b * BB + lane + 64 * j];
      }
      float g0[16];
      float* tbp = tileD + (size_t)pb * BB * BB;

      for (int ri = 0; ri < cnt; ++ri) {
        int R = start + ri;
        int unit = perm[pb * BB + R];
        const float* wrow = w + (size_t)unit * NN;
        const float4* wr4 = (const float4*)wrow;
        const float4* st4 = (const float4*)stateL;
        double acc = 0.0;
#pragma unroll
        for (int k = 0; k < NN / (4 * TPB); ++k) {   // 4 iters
          float4 a = wr4[tid + k * TPB];
          float4 s = st4[tid + k * TPB];
          acc += (double)(a.x * s.x) + (double)(a.y * s.y) +
                 (double)(a.z * s.z) + (double)(a.w * s.w);
        }
        for (int o = 32; o > 0; o >>= 1) acc += __shfl_down(acc, o, 64);
        if (lane == 0) redL[wv][ri] = acc;
        // tile gather (row is L1-hot)
        st_f32(&tbp[(size_t)R * BB + tid], wrow[pcA]);
        st_f32(&tbp[(size_t)R * BB + tid + 512], wrow[pcB]);
        if (pb > 0 && wv == ri) {                    // corr gather, owner wave
#pragma unroll
          for (int j = 0; j < 16; ++j) g0[j] = wrow[ppc[j]];
        }
      }
      __syncthreads();
      double Sraw = 0.0;
      if (wv < cnt) {
#pragma unroll
        for (int k = 0; k < 8; ++k) Sraw += redL[k][wv];
      }
      if (pb == 0) {
        if (wv < cnt && lane == 0) st_f64(&S[start + wv], Sraw);
        publish_flag(&slotCorr[iw]);
      } else {
        wait_flag(&delReady[b]);                     // del_b available
        if (wv < cnt) {
          double p = 0.0;
#pragma unroll
          for (int j = 0; j < 16; ++j)
            p += (double)(g0[j] * delG[b * BB + lane + 64 * j]);
          for (int o = 32; o > 0; o >>= 1) p += __shfl_down(p, o, 64);
          if (lane == 0) st_f64(&S[(size_t)pb * BB + start + wv], Sraw + p);
        }
        publish_flag(&slotCorr[(size_t)pb * NWORK + iw]);
        // advance private state with del_b
        for (int s = tid; s < BB; s += TPB)
          stateL[perm[b * BB + s]] += delG[b * BB + s];
        __syncthreads();
      }
    }
  }
}

extern "C" void kernel_launch(void* const* d_in, const int* in_sizes, int n_in,
                              void* d_out, int out_size, void* d_ws, size_t ws_size,
                              hipStream_t stream) {
  const float* w      = (const float*)d_in[0];
  const float* init   = (const float*)d_in[1];
  const float* clampv = (const float*)d_in[2];
  const float* Tp     = (const float*)d_in[3];
  const int*   perm   = (const int*)d_in[4];
  const float* urand  = (const float*)d_in[5];
  float* dout = (float*)d_out;

  double* thrG = (double*)d_ws;                       // NN
  double* S    = thrG + NN;                           // NBLK*BB = NN
  float* d1G   = (float*)(S + NN);                    // NN
  float* d0G   = d1G + NN;                            // NN
  float* delG  = d0G + NN;                            // NN
  float* tileD = delG + NN;                           // NBLK*BB*BB (32 MB)
  u32* slotCorr = (u32*)(tileD + (size_t)NBLK * BB * BB);  // NBLK*NWORK
  u32* delReady = slotCorr + NBLK * NWORK;                 // NBLK

  int nflags = NBLK * NWORK + NBLK;
  k_init<<<8, 256, 0, stream>>>(slotCorr, nflags);

  void* args[] = {(void*)&w, (void*)&init, (void*)&clampv, (void*)&Tp,
                  (void*)&perm, (void*)&urand, (void*)&dout,
                  (void*)&thrG, (void*)&S, (void*)&d1G, (void*)&d0G,
                  (void*)&delG, (void*)&tileD, (void*)&slotCorr, (void*)&delReady};
  hipLaunchCooperativeKernel((const void*)k_gibbs, dim3(NWG), dim3(TPB),
                             args, 0, stream);
}

// Round 6
// 575.115 us; speedup vs baseline: 3.0610x; 1.3521x over previous
//
#include <hip/hip_runtime.h>
#include <math.h>

// Boltzmann Gibbs sweep N=8192, single cooperative kernel.
// 16 blocks of BB=512. WG0 scans block b (8 x 64-step serial sub-scans,
// publishing del per sub-scan); 255 workers compute panel b+1 dots vs a
// private LDS state copy, gather the diag tile, and apply per-sub-del
// corrections IN REGISTERS; one ack per worker per block.
// Memory model: plain stores + publisher __threadfence + flag (release);
// WG0 acquires once per block (inv); workers read delG via relaxed
// agent-scope atomic loads only (no inv -> L2 stays warm).
// Decision: u <= sigmoid(s/T) <=> s >= T*log(u/(1-u)); thr fp64,
// POSITION-indexed (lax.scan zips (perm, rand_u)); clamp/state UNIT-indexed.
// All sums fp64; every correction product w*delta is exact in fp32.

#define NN 8192
#define BB 512
#define NBLK 16
#define SUB 64
#define NSUB 8
#define NWG 256
#define NWORK 255
#define TPB 512
#define MAXR 3

typedef unsigned int u32;

__global__ void k_init(u32* flags, int n) {
  int i = blockIdx.x * blockDim.x + threadIdx.x;
  for (; i < n; i += gridDim.x * blockDim.x) flags[i] = 0;
}

__device__ __forceinline__ u32 ld_rlx(const u32* p) {
  return __hip_atomic_load(p, __ATOMIC_RELAXED, __HIP_MEMORY_SCOPE_AGENT);
}
__device__ __forceinline__ u32 ld_acq(const u32* p) {
  return __hip_atomic_load(p, __ATOMIC_ACQUIRE, __HIP_MEMORY_SCOPE_AGENT);
}
__device__ __forceinline__ void st_rlx(u32* p, u32 v) {
  __hip_atomic_store(p, v, __ATOMIC_RELAXED, __HIP_MEMORY_SCOPE_AGENT);
}
__device__ __forceinline__ float ldf_rlx(const float* p) {
  return __hip_atomic_load(p, __ATOMIC_RELAXED, __HIP_MEMORY_SCOPE_AGENT);
}

__global__ __launch_bounds__(TPB) void k_gibbs(
    const float* __restrict__ w, const float* __restrict__ init,
    const float* __restrict__ clampv, const float* __restrict__ Tp,
    const int* __restrict__ perm, const float* __restrict__ urand,
    float* __restrict__ dout, double* __restrict__ S,
    float* __restrict__ delG, float* __restrict__ tileD,
    u32* subFlag, u32* ack) {
  __shared__ float stateL[NN];                     // workers (32 KB)
  __shared__ double sumsL[BB], thrL[BB];           // WG0 (8 KB)
  __shared__ float d1L[BB], d0L[BB], delL[BB], oldL[BB];
  __shared__ int uL[BB];
  __shared__ double redL[TPB / 64][MAXR];
  const int wg = blockIdx.x, tid = threadIdx.x;
  const int wv = tid >> 6, lane = tid & 63;

  if (wg == 0) {
    // ================= producer: serial scans =================
    double T = (double)Tp[0];
    for (int b = 0; b < NBLK; ++b) {
      // per-block tables (independent of workers -> before the wait)
      int pos = b * BB + tid;                      // TPB == BB
      int unit = perm[pos];
      double uu = (double)urand[pos];
      thrL[tid] = T * log(uu / (1.0 - uu));        // u==0 -> -inf -> always 1
      float old = init[unit];
      bool cl = (clampv[unit] != 0.0f);
      d1L[tid] = cl ? 0.0f : (1.0f - old);
      d0L[tid] = cl ? 0.0f : (0.0f - old);
      oldL[tid] = old;
      uL[tid] = unit;
      // wait: all workers acked block b (S[b] fully corrected, tile b ready)
      {
        const u32* slots = ack + (size_t)b * NWORK;
        for (;;) {
          int ok = 1;
          if (tid < NWORK) ok = (ld_rlx(&slots[tid]) != 0u);
          if (__syncthreads_and(ok)) break;
          __builtin_amdgcn_s_sleep(2);
        }
        if (tid == 0) (void)ld_acq(&slots[0]);     // acquire fence (inv)
        __syncthreads();
      }
      sumsL[tid] = S[(size_t)b * BB + tid];
      __syncthreads();
      const float* tb = tileD + (size_t)b * BB * BB;

      for (int t8 = 0; t8 < NSUB; ++t8) {
        float m[SUB];
        if (tid < SUB) {
          // diag 64x64 row -> registers (L3 latency hidden by near-pass)
          const float4* mr = (const float4*)(tb + (size_t)(t8 * SUB + tid) * BB + t8 * SUB);
#pragma unroll
          for (int j = 0; j < SUB / 4; ++j) {
            float4 v = mr[j];
            m[4*j] = v.x; m[4*j+1] = v.y; m[4*j+2] = v.z; m[4*j+3] = v.w;
          }
        } else if (t8 > 0) {
          // near-pass: apply del(t8-1) to the 64 rows about to be scanned
          int t = tid - SUB, g = t >> 2, sb = t & 3;
          if (g < SUB) {
            int row = t8 * SUB + g;
            int c0 = (t8 - 1) * SUB + sb * 16;
            const float4* mr2 = (const float4*)(tb + (size_t)row * BB + c0);
            double p = 0.0;
#pragma unroll
            for (int j = 0; j < 4; ++j) {
              float4 v = mr2[j];
              p += (double)(v.x * delL[c0+4*j])   + (double)(v.y * delL[c0+4*j+1]) +
                   (double)(v.z * delL[c0+4*j+2]) + (double)(v.w * delL[c0+4*j+3]);
            }
            p += __shfl_down(p, 2, 4);
            p += __shfl_down(p, 1, 4);
            if (sb == 0) sumsL[row] += p;
          }
        }
        __syncthreads();
        if (tid < SUB) {
          // serial 64-step sub-scan (wave 0)
          int row = t8 * SUB + tid;
          double sum = sumsL[row], th = thrL[row];
          float dd1 = d1L[row], dd0 = d0L[row];
          float mydel = 0.0f;
          __builtin_amdgcn_s_setprio(3);
#pragma unroll
          for (int s = 0; s < SUB; ++s) {
            float down = (sum >= th) ? dd1 : dd0;
            float sd = __uint_as_float(__builtin_amdgcn_readlane(__float_as_uint(down), s));
            if (s == tid) mydel = down;
            sum += (double)(m[s] * sd);            // exact fp32 product
          }
          __builtin_amdgcn_s_setprio(0);
          delL[row] = mydel;
          if (b + 1 < NBLK) {
            delG[b * BB + row] = mydel;            // 256 B payload
            __threadfence();                       // tiny dirty set -> cheap
            if (tid == 0) st_rlx(&subFlag[b * NSUB + t8], 1u);
          }
        } else if (t8 > 0) {
          // far-pass: apply del(t8-1) to rows beyond sub t8 (hidden under serial)
          for (int r = (t8 + 1) * SUB + (tid - SUB); r < BB; r += (TPB - SUB)) {
            int c0 = (t8 - 1) * SUB;
            const float4* mr3 = (const float4*)(tb + (size_t)r * BB + c0);
            double acc = sumsL[r];
#pragma unroll
            for (int j = 0; j < SUB / 4; ++j) {
              float4 v = mr3[j];
              acc += (double)(v.x * delL[c0+4*j])   + (double)(v.y * delL[c0+4*j+1]) +
                     (double)(v.z * delL[c0+4*j+2]) + (double)(v.w * delL[c0+4*j+3]);
            }
            sumsL[r] = acc;
          }
        }
        __syncthreads();
      }
      dout[uL[tid]] = oldL[tid] + delL[tid];       // exact {0,1} / clamped init
    }
  } else {
    // ================= workers =================
    const int iw = wg - 1;
    const int r0 = (iw * BB) / NWORK, r1 = ((iw + 1) * BB) / NWORK;
    const int cnt = r1 - r0;                       // 2..3
    for (int i = tid; i < NN; i += TPB) stateL[i] = init[i];
    __syncthreads();

    for (int p = 0; p < NBLK; ++p) {
      int pc = perm[p * BB + tid];                 // tile col units
      float g[NSUB];                               // my row's correction strip
      float* tbp = tileD + (size_t)p * BB * BB;

      for (int ri = 0; ri < cnt; ++ri) {
        int unit = perm[p * BB + r0 + ri];
        const float* wrow = w + (size_t)unit * NN;
        const float4* wr4 = (const float4*)wrow;
        const float4* st4 = (const float4*)stateL;
        double acc = 0.0;
#pragma unroll
        for (int k = 0; k < NN / (4 * TPB); ++k) { // 4 iters
          float4 a = wr4[tid + k * TPB];
          float4 s = st4[tid + k * TPB];
          acc += (double)(a.x * s.x) + (double)(a.y * s.y) +
                 (double)(a.z * s.z) + (double)(a.w * s.w);
        }
        for (int o = 32; o > 0; o >>= 1) acc += __shfl_down(acc, o, 64);
        if (lane == 0) redL[wv][ri] = acc;
        tbp[(size_t)(r0 + ri) * BB + tid] = wrow[pc];   // tile row (L1-hot)
        if (p > 0 && wv == ri) {                   // my row's strip vs block p-1
#pragma unroll
          for (int t8 = 0; t8 < NSUB; ++t8)
            g[t8] = wrow[perm[(p - 1) * BB + t8 * SUB + lane]];
        }
      }
      __syncthreads();
      double Sr = 0.0;
      if (wv < cnt) {
#pragma unroll
        for (int k = 0; k < TPB / 64; ++k) Sr += redL[k][wv];
      }
      if (p > 0) {
        // incremental in-register corrections as sub-dels arrive
        double crr = 0.0;
        for (int t8 = 0; t8 < NSUB; ++t8) {
          const u32* f = &subFlag[(p - 1) * NSUB + t8];
          if (tid == 0) {
            while (ld_rlx(f) == 0u) __builtin_amdgcn_s_sleep(2);
          }
          __syncthreads();
          float dl = ldf_rlx(&delG[(p - 1) * BB + t8 * SUB + lane]);
          if (wv < cnt) crr += (double)(g[t8] * dl);      // exact product
          if (tid < SUB) stateL[perm[(p - 1) * BB + t8 * SUB + tid]] += dl;
        }
        for (int o = 32; o > 0; o >>= 1) crr += __shfl_down(crr, o, 64);
        Sr += crr;
        __syncthreads();
      }
      if (wv < cnt && lane == 0) S[(size_t)p * BB + r0 + wv] = Sr;
      __syncthreads();
      if (tid == 0) {
        __threadfence();                           // flush tile rows + S (small)
        st_rlx(&ack[(size_t)p * NWORK + iw], 1u);
      }
      __syncthreads();
    }
  }
}

extern "C" void kernel_launch(void* const* d_in, const int* in_sizes, int n_in,
                              void* d_out, int out_size, void* d_ws, size_t ws_size,
                              hipStream_t stream) {
  const float* w      = (const float*)d_in[0];
  const float* init   = (const float*)d_in[1];
  const float* clampv = (const float*)d_in[2];
  const float* Tp     = (const float*)d_in[3];
  const int*   perm   = (const int*)d_in[4];
  const float* urand  = (const float*)d_in[5];
  float* dout = (float*)d_out;

  double* S    = (double*)d_ws;                        // NN doubles
  float* delG  = (float*)(S + NN);                     // NN
  float* tileD = delG + NN;                            // NBLK*BB*BB (16 MB)
  u32* subFlag = (u32*)(tileD + (size_t)NBLK * BB * BB);  // NBLK*NSUB
  u32* ack     = subFlag + NBLK * NSUB;                   // NBLK*NWORK

  int nflags = NBLK * NSUB + NBLK * NWORK;
  k_init<<<8, 256, 0, stream>>>(subFlag, nflags);

  void* args[] = {(void*)&w, (void*)&init, (void*)&clampv, (void*)&Tp,
                  (void*)&perm, (void*)&urand, (void*)&dout,
                  (void*)&S, (void*)&delG, (void*)&tileD,
                  (void*)&subFlag, (void*)&ack};
  hipLaunchCooperativeKernel((const void*)k_gibbs, dim3(NWG), dim3(TPB),
                             args, 0, stream);
}

// Round 7
// 508.642 us; speedup vs baseline: 3.4610x; 1.1307x over previous
//
#include <hip/hip_runtime.h>
#include <math.h>

// Boltzmann Gibbs sweep N=8192, single cooperative kernel, fence-free pipeline.
// 16 blocks of BB=512. WG0 scans block b (8 x 64-step serial sub-scans);
// 255 workers compute panel b+1 dots vs private LDS state + gather diag tile,
// and apply per-sub-del corrections in registers; one ack per worker per block.
// Memory model: ALL cross-WG payloads use agent-scope relaxed atomic (sc1,
// write-through-to-L3) stores; ordering = wave vmcnt drain at __syncthreads,
// then relaxed flag store. No buffer_wbl2 / buffer_inv anywhere on the path.
// WG0 prefetches diag m-tile (double-buffered regs) and near-strips (regs)
// during the serial chain, so each phase starts without an L3 round trip.
// Decision: u <= sigmoid(s/T) <=> s >= T*log(u/(1-u)); thr fp64,
// POSITION-indexed (lax.scan zips (perm, rand_u)); clamp/state UNIT-indexed.
// All sums fp64; every correction product w*delta is exact in fp32.
// Reduction trees bit-identical to the round-6 passing kernel.

#define NN 8192
#define BB 512
#define NBLK 16
#define SUB 64
#define NSUB 8
#define NWG 256
#define NWORK 255
#define TPB 512
#define MAXR 3

typedef unsigned int u32;

__global__ void k_init(u32* flags, int n) {
  int i = blockIdx.x * blockDim.x + threadIdx.x;
  for (; i < n; i += gridDim.x * blockDim.x) flags[i] = 0;
}

__device__ __forceinline__ u32 ld_rlx(const u32* p) {
  return __hip_atomic_load(p, __ATOMIC_RELAXED, __HIP_MEMORY_SCOPE_AGENT);
}
__device__ __forceinline__ void st_rlx(u32* p, u32 v) {
  __hip_atomic_store(p, v, __ATOMIC_RELAXED, __HIP_MEMORY_SCOPE_AGENT);
}
__device__ __forceinline__ float ldf_rlx(const float* p) {
  return __hip_atomic_load(p, __ATOMIC_RELAXED, __HIP_MEMORY_SCOPE_AGENT);
}
__device__ __forceinline__ void stf_rlx(float* p, float v) {
  __hip_atomic_store(p, v, __ATOMIC_RELAXED, __HIP_MEMORY_SCOPE_AGENT);
}
__device__ __forceinline__ double ldd_rlx(const double* p) {
  return __hip_atomic_load(p, __ATOMIC_RELAXED, __HIP_MEMORY_SCOPE_AGENT);
}
__device__ __forceinline__ void std_rlx(double* p, double v) {
  __hip_atomic_store(p, v, __ATOMIC_RELAXED, __HIP_MEMORY_SCOPE_AGENT);
}

// wave0: load 64x64 diag tile row into registers
#define LOADM(MARR, T8N) do {                                                  \
  const float4* mr_ = (const float4*)(tb + (size_t)((T8N) * SUB + tid) * BB + (T8N) * SUB); \
  _Pragma("unroll")                                                            \
  for (int j_ = 0; j_ < SUB / 4; ++j_) {                                       \
    float4 v_ = mr_[j_];                                                       \
    MARR[4*j_] = v_.x; MARR[4*j_+1] = v_.y;                                    \
    MARR[4*j_+2] = v_.z; MARR[4*j_+3] = v_.w; }                                \
} while (0)

// wave0: serial 64-step sub-scan
#define CHAIN(MARR, T8C) do {                                                  \
  int row_ = (T8C) * SUB + tid;                                                \
  double sum_ = sumsL[row_], th_ = thrL[row_];                                 \
  float dd1_ = d1L[row_], dd0_ = d0L[row_];                                    \
  float mydel_ = 0.0f;                                                         \
  __builtin_amdgcn_s_setprio(3);                                               \
  _Pragma("unroll")                                                            \
  for (int s_ = 0; s_ < SUB; ++s_) {                                           \
    float down_ = (sum_ >= th_) ? dd1_ : dd0_;                                 \
    float sd_ = __uint_as_float(                                               \
        __builtin_amdgcn_readlane(__float_as_uint(down_), s_));                \
    if (s_ == tid) mydel_ = down_;                                             \
    sum_ += (double)(MARR[s_] * sd_); }                                        \
  __builtin_amdgcn_s_setprio(0);                                               \
  delL[row_] = mydel_;                                                         \
  if (pub) stf_rlx(&delG[b * BB + row_], mydel_);                              \
} while (0)

__global__ __launch_bounds__(TPB) void k_gibbs(
    const float* __restrict__ w, const float* __restrict__ init,
    const float* __restrict__ clampv, const float* __restrict__ Tp,
    const int* __restrict__ perm, const float* __restrict__ urand,
    float* __restrict__ dout, double* __restrict__ S,
    float* __restrict__ delG, float* __restrict__ tileD,
    u32* subFlag, u32* ack) {
  __shared__ float stateL[NN];                     // workers (32 KB)
  __shared__ double sumsL[BB], thrL[BB];           // WG0 (8 KB)
  __shared__ float d1L[BB], d0L[BB], delL[BB], oldL[BB];
  __shared__ int uL[BB];
  __shared__ double redL[TPB / 64][MAXR];
  const int wg = blockIdx.x, tid = threadIdx.x;
  const int wv = tid >> 6, lane = tid & 63;

  if (wg == 0) {
    // ================= producer: serial scans =================
    double T = (double)Tp[0];
    for (int b = 0; b < NBLK; ++b) {
      const bool pub = (b + 1 < NBLK);
      // per-block tables (independent of workers -> before the wait)
      int pos = b * BB + tid;                      // TPB == BB
      int unit = perm[pos];
      double uu = (double)urand[pos];
      thrL[tid] = T * log(uu / (1.0 - uu));        // u==0 -> -inf -> always 1
      float old = init[unit];
      bool cl = (clampv[unit] != 0.0f);
      d1L[tid] = cl ? 0.0f : (1.0f - old);
      d0L[tid] = cl ? 0.0f : (0.0f - old);
      oldL[tid] = old;
      uL[tid] = unit;
      // wait: all workers acked block b (S[b] corrected, tile b in L3)
      {
        const u32* slots = ack + (size_t)b * NWORK;
        for (;;) {
          int ok = 1;
          if (tid < NWORK) ok = (ld_rlx(&slots[tid]) != 0u);
          if (__syncthreads_and(ok)) break;
          __builtin_amdgcn_s_sleep(1);
        }
      }
      sumsL[tid] = ldd_rlx(&S[(size_t)b * BB + tid]);
      __syncthreads();
      const float* tb = tileD + (size_t)b * BB * BB;
      float mA[SUB], mB[SUB];
      float4 nv0, nv1, nv2, nv3;                   // near-strip prefetch regs
      if (tid < SUB) LOADM(mA, 0);

      for (int t8 = 0; t8 < NSUB; ++t8) {
        // ---- A section: publish del(t8-1) + register near-fma ----
        if (t8 > 0) {
          if (pub && tid == 0) st_rlx(&subFlag[b * NSUB + (t8 - 1)], 1u);
          if (tid >= 256) {
            int t = tid - 256;                     // 0..255
            int rrow = t8 * SUB + (t >> 2);
            int q = t & 3;
            int c0 = (t8 - 1) * SUB + q * 16;
            double p_ =
                (double)(nv0.x * delL[c0])    + (double)(nv0.y * delL[c0+1]) +
                (double)(nv0.z * delL[c0+2])  + (double)(nv0.w * delL[c0+3]) +
                (double)(nv1.x * delL[c0+4])  + (double)(nv1.y * delL[c0+5]) +
                (double)(nv1.z * delL[c0+6])  + (double)(nv1.w * delL[c0+7]);
            p_ +=
                (double)(nv2.x * delL[c0+8])  + (double)(nv2.y * delL[c0+9]) +
                (double)(nv2.z * delL[c0+10]) + (double)(nv2.w * delL[c0+11]) +
                (double)(nv3.x * delL[c0+12]) + (double)(nv3.y * delL[c0+13]) +
                (double)(nv3.z * delL[c0+14]) + (double)(nv3.w * delL[c0+15]);
            p_ += __shfl_down(p_, 2, 4);
            p_ += __shfl_down(p_, 1, 4);
            if (q == 0) sumsL[rrow] += p_;
          }
        }
        __syncthreads();
        // ---- B section: chain || prefetch || far-pass ----
        if (tid < SUB) {
          if (t8 & 1) { if (t8 < NSUB - 1) LOADM(mA, t8 + 1); CHAIN(mB, t8); }
          else        { if (t8 < NSUB - 1) LOADM(mB, t8 + 1); CHAIN(mA, t8); }
        } else {
          if (t8 < NSUB - 1 && tid >= 256) {
            // prefetch near-strip: rows sub(t8+1), cols sub(t8)
            int t = tid - 256;
            const float4* pr = (const float4*)(
                tb + (size_t)((t8 + 1) * SUB + (t >> 2)) * BB + t8 * SUB + (t & 3) * 16);
            nv0 = pr[0]; nv1 = pr[1]; nv2 = pr[2]; nv3 = pr[3];
          }
          if (t8 > 0) {
            // far-pass: apply del(t8-1) to rows beyond sub t8
            for (int r = (t8 + 1) * SUB + (tid - SUB); r < BB; r += (TPB - SUB)) {
              int c0 = (t8 - 1) * SUB;
              const float4* mr3 = (const float4*)(tb + (size_t)r * BB + c0);
              double acc = sumsL[r];
#pragma unroll
              for (int j = 0; j < SUB / 4; ++j) {
                float4 v = mr3[j];
                acc += (double)(v.x * delL[c0+4*j])   + (double)(v.y * delL[c0+4*j+1]) +
                       (double)(v.z * delL[c0+4*j+2]) + (double)(v.w * delL[c0+4*j+3]);
              }
              sumsL[r] = acc;
            }
          }
        }
        __syncthreads();                            // drains delG stores (vmcnt)
      }
      if (pub && tid == 0) st_rlx(&subFlag[b * NSUB + (NSUB - 1)], 1u);
      dout[uL[tid]] = oldL[tid] + delL[tid];        // exact {0,1} / clamped init
    }
  } else {
    // ================= workers =================
    const int iw = wg - 1;
    const int r0 = (iw * BB) / NWORK, r1 = ((iw + 1) * BB) / NWORK;
    const int cnt = r1 - r0;                        // 2..3
    for (int i = tid; i < NN; i += TPB) stateL[i] = init[i];
    __syncthreads();

    for (int p = 0; p < NBLK; ++p) {
      int pc = perm[p * BB + tid];                  // tile col units
      float g[NSUB];                                // my row's corr strip
      float* tbp = tileD + (size_t)p * BB * BB;

      for (int ri = 0; ri < cnt; ++ri) {
        int unit = perm[p * BB + r0 + ri];
        const float* wrow = w + (size_t)unit * NN;
        const float4* wr4 = (const float4*)wrow;
        const float4* st4 = (const float4*)stateL;
        double acc = 0.0;
#pragma unroll
        for (int k = 0; k < NN / (4 * TPB); ++k) {  // 4 iters
          float4 a = wr4[tid + k * TPB];
          float4 s = st4[tid + k * TPB];
          acc += (double)(a.x * s.x) + (double)(a.y * s.y) +
                 (double)(a.z * s.z) + (double)(a.w * s.w);
        }
        for (int o = 32; o > 0; o >>= 1) acc += __shfl_down(acc, o, 64);
        if (lane == 0) redL[wv][ri] = acc;
        stf_rlx(&tbp[(size_t)(r0 + ri) * BB + tid], wrow[pc]);   // tile row (sc1)
        if (p > 0 && wv == ri) {                    // my row's strip vs block p-1
#pragma unroll
          for (int t8 = 0; t8 < NSUB; ++t8)
            g[t8] = wrow[perm[(p - 1) * BB + t8 * SUB + lane]];
        }
      }
      __syncthreads();
      double Sr = 0.0;
      if (wv < cnt) {
#pragma unroll
        for (int k = 0; k < TPB / 64; ++k) Sr += redL[k][wv];
      }
      if (p > 0) {
        // incremental in-register corrections as sub-dels arrive
        double crr = 0.0;
        for (int t8 = 0; t8 < NSUB; ++t8) {
          const u32* f = &subFlag[(p - 1) * NSUB + t8];
          if (tid == 0) {
            while (ld_rlx(f) == 0u) __builtin_amdgcn_s_sleep(1);
          }
          __syncthreads();
          float dl = ldf_rlx(&delG[(p - 1) * BB + t8 * SUB + lane]);
          if (wv < cnt) crr += (double)(g[t8] * dl);       // exact product
          if (tid < SUB) stateL[perm[(p - 1) * BB + t8 * SUB + tid]] += dl;
        }
        for (int o = 32; o > 0; o >>= 1) crr += __shfl_down(crr, o, 64);
        Sr += crr;
      }
      if (wv < cnt && lane == 0) std_rlx(&S[(size_t)p * BB + r0 + wv], Sr);
      __syncthreads();                              // drain all waves' sc1 stores
      if (tid == 0) st_rlx(&ack[(size_t)p * NWORK + iw], 1u);
    }
  }
}

extern "C" void kernel_launch(void* const* d_in, const int* in_sizes, int n_in,
                              void* d_out, int out_size, void* d_ws, size_t ws_size,
                              hipStream_t stream) {
  const float* w      = (const float*)d_in[0];
  const float* init   = (const float*)d_in[1];
  const float* clampv = (const float*)d_in[2];
  const float* Tp     = (const float*)d_in[3];
  const int*   perm   = (const int*)d_in[4];
  const float* urand  = (const float*)d_in[5];
  float* dout = (float*)d_out;

  double* S    = (double*)d_ws;                        // NN doubles
  float* delG  = (float*)(S + NN);                     // NN
  float* tileD = delG + NN;                            // NBLK*BB*BB (16 MB)
  u32* subFlag = (u32*)(tileD + (size_t)NBLK * BB * BB);  // NBLK*NSUB
  u32* ack     = subFlag + NBLK * NSUB;                   // NBLK*NWORK

  int nflags = NBLK * NSUB + NBLK * NWORK;
  k_init<<<8, 256, 0, stream>>>(subFlag, nflags);

  void* args[] = {(void*)&w, (void*)&init, (void*)&clampv, (void*)&Tp,
                  (void*)&perm, (void*)&urand, (void*)&dout,
                  (void*)&S, (void*)&delG, (void*)&tileD,
                  (void*)&subFlag, (void*)&ack};
  hipLaunchCooperativeKernel((const void*)k_gibbs, dim3(NWG), dim3(TPB),
                             args, 0, stream);
}